// Round 2
// baseline (328.234 us; speedup 1.0000x reference)
//
#include <hip/hip_runtime.h>

// out[b,h,w,c] = sum_j w[j,c] * t_j[b,h,w,c]
// B,H,W,C = 8,128,128,128 -> N = 16,777,216 f32 elements, nvec = 4,194,304 float4.
// Pure HBM-bound elementwise: 320 MiB read + 64 MiB write per call.
//
// v3 = v2 with native vector type (ext_vector_type) so
// __builtin_nontemporal_store compiles (HIP's float4 class is rejected).
//
// v2 changes vs baseline (117 us/dispatch, 3.43 TB/s effective):
//  - 4 float4 per thread, strided by total thread count T. T is a multiple of
//    32, so (idx & 31) -> channel base c4 is invariant across all 4 elements:
//    the 5 weight float4s are loaded ONCE per thread (was 4x).
//  - All 20 tensor loads issued in one unguarded batch on the fast path.
//  - Non-temporal stores: output is write-once; keep it out of L2/LLC so the
//    Infinity Cache retains more of the 320 MiB input set across iterations
//    (FETCH_SIZE was ~160 MB vs 320 MiB logical reads -> ~50% LLC hit;
//    the 64 MiB/iter write allocation was evicting inputs).

typedef float f4 __attribute__((ext_vector_type(4)));

__global__ __launch_bounds__(256) void merge5_kernel(
    const float* __restrict__ t1, const float* __restrict__ t2,
    const float* __restrict__ t3, const float* __restrict__ t4,
    const float* __restrict__ t5, const float* __restrict__ w,
    float* __restrict__ out, int nvec, int T)
{
    int idx = blockIdx.x * 256 + threadIdx.x;
    if (idx >= T) return;

    // channel base for this float4 (C=128 -> 32 float4s per channel period).
    // T % 32 == 0, so c4 is the same for idx, idx+T, idx+2T, idx+3T.
    int c4 = (idx & 31) << 2;

    const f4 w0 = *(const f4*)(w + 0 * 128 + c4);
    const f4 w1 = *(const f4*)(w + 1 * 128 + c4);
    const f4 w2 = *(const f4*)(w + 2 * 128 + c4);
    const f4 w3 = *(const f4*)(w + 3 * 128 + c4);
    const f4 w4 = *(const f4*)(w + 4 * 128 + c4);

    const f4* p1 = (const f4*)t1;
    const f4* p2 = (const f4*)t2;
    const f4* p3 = (const f4*)t3;
    const f4* p4 = (const f4*)t4;
    const f4* p5 = (const f4*)t5;
    f4* po = (f4*)out;

    int i0 = idx, i1 = idx + T, i2 = idx + 2 * T, i3 = idx + 3 * T;

    if (i3 < nvec) {
        // Fast path: all 20 loads issued back-to-back, no guards.
        f4 a0 = p1[i0], a1 = p1[i1], a2 = p1[i2], a3 = p1[i3];
        f4 b0 = p2[i0], b1 = p2[i1], b2 = p2[i2], b3 = p2[i3];
        f4 c0 = p3[i0], c1 = p3[i1], c2 = p3[i2], c3 = p3[i3];
        f4 d0 = p4[i0], d1 = p4[i1], d2 = p4[i2], d3 = p4[i3];
        f4 e0 = p5[i0], e1 = p5[i1], e2 = p5[i2], e3 = p5[i3];

        f4 r0 = a0 * w0 + b0 * w1 + c0 * w2 + d0 * w3 + e0 * w4;
        f4 r1 = a1 * w0 + b1 * w1 + c1 * w2 + d1 * w3 + e1 * w4;
        f4 r2 = a2 * w0 + b2 * w1 + c2 * w2 + d2 * w3 + e2 * w4;
        f4 r3 = a3 * w0 + b3 * w1 + c3 * w2 + d3 * w3 + e3 * w4;

        __builtin_nontemporal_store(r0, po + i0);
        __builtin_nontemporal_store(r1, po + i1);
        __builtin_nontemporal_store(r2, po + i2);
        __builtin_nontemporal_store(r3, po + i3);
    } else {
        // Tail path (never taken for the bench shape, kept for generality).
        int ii[4] = {i0, i1, i2, i3};
        for (int k = 0; k < 4; ++k) {
            int i = ii[k];
            if (i >= nvec) break;
            f4 a = p1[i], b = p2[i], c = p3[i], d = p4[i], e = p5[i];
            f4 r = a * w0 + b * w1 + c * w2 + d * w3 + e * w4;
            __builtin_nontemporal_store(r, po + i);
        }
    }
}

extern "C" void kernel_launch(void* const* d_in, const int* in_sizes, int n_in,
                              void* d_out, int out_size, void* d_ws, size_t ws_size,
                              hipStream_t stream) {
    const float* t1 = (const float*)d_in[0];
    const float* t2 = (const float*)d_in[1];
    const float* t3 = (const float*)d_in[2];
    const float* t4 = (const float*)d_in[3];
    const float* t5 = (const float*)d_in[4];
    const float* w  = (const float*)d_in[5];
    float* out = (float*)d_out;

    int nvec = out_size / 4;                 // 4,194,304 float4s
    // Threads: nvec/4 rounded up to a multiple of 32 so (idx & 31) is
    // invariant across the 4 strided elements each thread handles.
    int T = ((nvec + 3) / 4 + 31) & ~31;     // 1,048,576 for the bench shape
    int blocks = (T + 255) / 256;            // 4096

    merge5_kernel<<<blocks, 256, 0, stream>>>(t1, t2, t3, t4, t5, w, out, nvec, T);
}

// Round 3
// 310.180 us; speedup vs baseline: 1.0582x; 1.0582x over previous
//
#include <hip/hip_runtime.h>

// out[b,h,w,c] = sum_j w[j,c] * t_j[b,h,w,c]
// B,H,W,C = 8,128,128,128 -> N = 16,777,216 f32, nvec = 4,194,304 float4.
// Pure HBM-bound elementwise: 320 MiB read + 64 MiB write per call.
//
// History:
//  v1: 1 float4/thread, 16384 one-shot blocks, plain stores -> 117 us,
//      2.0 TB/s counted HBM (FETCH 164 MB + WRITE 64 MiB), VALUBusy 1.9%.
//  v3: 4x/thread strided 16 MiB + NT stores -> 146 us REGRESSION.
//      FETCH identical -> LLC-retention theory dead; giant strides broke
//      DRAM page locality (24 streams/wave).
//  v4: contiguous block tiles + in-block grid-stride (this file).
//      2048 blocks x 256 threads x 8 float4/thread; each block owns a
//      CONTIGUOUS 32 KiB tile per stream; thread iteration stride is only
//      4 KiB. Waves stay at 6 DRAM streams, bursts stay contiguous, and
//      per-wave setup cost (kernarg loads, addressing, launch/drain) is
//      amortized 8x vs v1's 65K single-shot waves. Plain stores (NT reverted).

typedef float f4 __attribute__((ext_vector_type(4)));

#define TPB 256
#define KPT 8              // float4s per thread
#define TILE (TPB * KPT)   // 2048 float4s = 32 KiB per stream per block

__global__ __launch_bounds__(256) void merge5_kernel(
    const float* __restrict__ t1, const float* __restrict__ t2,
    const float* __restrict__ t3, const float* __restrict__ t4,
    const float* __restrict__ t5, const float* __restrict__ w,
    float* __restrict__ out, int nvec)
{
    int tid = threadIdx.x;
    int base = blockIdx.x * TILE + tid;

    // channel base: C=128 -> 32 f4 per channel period; TILE and TPB are
    // multiples of 32, so (base & 31) == (tid & 31) for every iteration.
    int c4 = (tid & 31) << 2;

    const f4 w0 = *(const f4*)(w + 0 * 128 + c4);
    const f4 w1 = *(const f4*)(w + 1 * 128 + c4);
    const f4 w2 = *(const f4*)(w + 2 * 128 + c4);
    const f4 w3 = *(const f4*)(w + 3 * 128 + c4);
    const f4 w4 = *(const f4*)(w + 4 * 128 + c4);

    const f4* p1 = (const f4*)t1;
    const f4* p2 = (const f4*)t2;
    const f4* p3 = (const f4*)t3;
    const f4* p4 = (const f4*)t4;
    const f4* p5 = (const f4*)t5;
    f4* po = (f4*)out;

    if (base + (KPT - 1) * TPB < nvec) {
        // Fast path: whole tile in range (always true for the bench shape).
#pragma unroll 2
        for (int k = 0; k < KPT; ++k) {
            int i = base + k * TPB;
            f4 a = p1[i], b = p2[i], c = p3[i], d = p4[i], e = p5[i];
            po[i] = a * w0 + b * w1 + c * w2 + d * w3 + e * w4;
        }
    } else {
        // Tail path (not taken for the bench shape).
        for (int k = 0; k < KPT; ++k) {
            int i = base + k * TPB;
            if (i < nvec) {
                f4 a = p1[i], b = p2[i], c = p3[i], d = p4[i], e = p5[i];
                po[i] = a * w0 + b * w1 + c * w2 + d * w3 + e * w4;
            }
        }
    }
}

extern "C" void kernel_launch(void* const* d_in, const int* in_sizes, int n_in,
                              void* d_out, int out_size, void* d_ws, size_t ws_size,
                              hipStream_t stream) {
    const float* t1 = (const float*)d_in[0];
    const float* t2 = (const float*)d_in[1];
    const float* t3 = (const float*)d_in[2];
    const float* t4 = (const float*)d_in[3];
    const float* t5 = (const float*)d_in[4];
    const float* w  = (const float*)d_in[5];
    float* out = (float*)d_out;

    int nvec = out_size / 4;                    // 4,194,304 float4s
    int blocks = (nvec + TILE - 1) / TILE;      // 2048 -> 8 blocks/CU

    merge5_kernel<<<blocks, TPB, 0, stream>>>(t1, t2, t3, t4, t5, w, out, nvec);
}